// Round 11
// baseline (43.222 us; speedup 1.0000x reference)
//
#include <hip/hip_runtime.h>
#include <math.h>

namespace {

constexpr int IMG  = 128;
constexpr int NPIX = IMG * IMG;
constexpr int B    = 4;
constexpr int V    = 600;
constexpr int F    = 1000;
constexpr float FOCALF = 1.5f;
constexpr float EPSF   = 1e-8f;
constexpr float SLACK  = 1e-5f;     // >> max rounding error of w (~3e-6)
// early-z: z_inside >= min3(vz) - 0.022 when |den|>=1e-3 (sum(s_i) = 1 +- 1e-2)
constexpr float ZMARGIN = 0.03f;
constexpr float DENSAFE = 1e-3f;

__device__ inline float rlane(float x, int s) {
    return __uint_as_float(__builtin_amdgcn_readlane(__float_as_uint(x), s));
}

__device__ inline float seg_dist2(float px, float py, float ax, float ay,
                                  float bx, float by) {
#pragma clang fp contract(off)
    float ex = bx - ax, ey = by - ay;
    float dx = px - ax, dy = py - ay;
    float ee = fmaxf(ex * ex + ey * ey, EPSF);
    float t  = (dx * ex + dy * ey) / ee;
    t = fminf(fmaxf(t, 0.0f), 1.0f);
    float rx = dx - t * ex;
    float ry = dy - t * ey;
    return rx * rx + ry * ry;
}

// facedata layout [b][f][16]:
//  0:e0x 1:e0y 2:bx 3:by | 4:e1x 5:e1y 6:cx 7:cy | 8:e2x 9:e2y 10:ax 11:ay |
// 12:den 13:az 14:bz 15:cz      (den==0 marks degenerate/culled)
// Also clears zbest (one u64 per pixel) — fused to save a launch.
__global__ __launch_bounds__(256) void setup_clear(const float* __restrict__ verts,
                                                   const int* __restrict__ faces,
                                                   float* __restrict__ fdata,
                                                   unsigned long long* __restrict__ zbest) {
#pragma clang fp contract(off)
    int t = blockIdx.x * 256 + threadIdx.x;   // grid covers B*NPIX = 65536
    zbest[t] = ~0ULL;
    if (t >= B * F) return;
    int b = t / F, f = t - b * F;
    int i0 = faces[f * 3 + 0], i1 = faces[f * 3 + 1], i2 = faces[f * 3 + 2];
    const float* vb = verts + (size_t)b * V * 3;
    float x0 = vb[i0 * 3], y0 = vb[i0 * 3 + 1], z0 = vb[i0 * 3 + 2];
    float x1 = vb[i1 * 3], y1 = vb[i1 * 3 + 1], z1 = vb[i1 * 3 + 2];
    float x2 = vb[i2 * 3], y2 = vb[i2 * 3 + 1], z2 = vb[i2 * 3 + 2];
    // exact reference projection
    float ax = (FOCALF * x0) / z0, ay = (FOCALF * y0) / z0;
    float bx = (FOCALF * x1) / z1, by = (FOCALF * y1) / z1;
    float cx = (FOCALF * x2) / z2, cy = (FOCALF * y2) / z2;
    // edge vectors (identical rounding to reference's inline subtractions)
    float e0x = cx - bx, e0y = cy - by;   // edge for w0 (v1->v2), base b
    float e1x = ax - cx, e1y = ay - cy;   // edge for w1 (v2->v0), base c
    float e2x = bx - ax, e2y = by - ay;   // edge for w2 (v0->v1), base a
    float den = e2x * (cy - ay) - e2y * (cx - ax);   // == reference area tree
    if (!(fabsf(den) > EPSF)) den = 0.0f;
    float* o = fdata + ((size_t)t << 4);
    o[0]  = e0x; o[1]  = e0y; o[2]  = bx;  o[3]  = by;
    o[4]  = e1x; o[5]  = e1y; o[6]  = cx;  o[7]  = cy;
    o[8]  = e2x; o[9]  = e2y; o[10] = ax;  o[11] = ay;
    o[12] = den; o[13] = z0;  o[14] = z1;  o[15] = z2;
}

// Fused bin+shade. 1024 blocks x 512 thr (8 waves). Block = (ch, b, slice):
// one 64-face chunk (pinned in registers, one face per lane) x 16 tiles
// (4x4 lattice over the image, stratified). 8 waves pull tiles off an LDS
// ticket. Survivor loop pops TWO faces per iteration and evaluates both in
// one straight-line body so the two readlane/edge/divide chains interleave
// (2x ILP); per-lane merges stay gated -> merged values bit-identical.
__global__ __launch_bounds__(512, 8) void rast(const float* __restrict__ fdata,
                                               unsigned long long* __restrict__ zbest) {
#pragma clang fp contract(off)
    __shared__ unsigned int lticket;
    const int tid  = threadIdx.x;
    const int lane = tid & 63;
    const int bk   = blockIdx.x;
    const int ch   = bk & 15;          // face chunk
    const int b    = (bk >> 4) & 3;    // image
    const int slice = bk >> 6;         // 0..15 -> 4x4 lattice phase
    if (tid == 0) lticket = 0u;
    __syncthreads();

    // pin this chunk's face data: one face per lane, lives in VGPRs
    const int f0 = ch * 64;
    const int sz = min(64, F - f0);    // 64, last chunk 40
    const int fl = min(f0 + lane, F - 1);
    const float4* fd4 = (const float4*)(fdata + (((size_t)b * F + fl) << 4));
    const float4 q0 = fd4[0], q1 = fd4[1], q2 = fd4[2], q3 = fd4[3];
    const bool valid = (lane < sz) & (q3.x != 0.0f);
    const float s = q3.x > 0.0f ? 1.0f : -1.0f;
    // sign-folded gradients + corner-select bits: fixed per lane, once
    const float g0x = s * q0.x, g0y = s * q0.y;
    const float g1x = s * q1.x, g1y = s * q1.y;
    const float g2x = s * q2.x, g2y = s * q2.y;
    const bool c0y = g0x >= 0.0f, c0x = g0y >= 0.0f;
    const bool c1y = g1x >= 0.0f, c1x = g1y >= 0.0f;
    const bool c2y = g2x >= 0.0f, c2x = g2y >= 0.0f;
    // early-z threshold per face: min vertex z minus safety margin;
    // slivers (|den| < 1e-3) are never skipped (sum(s_i) unbounded there)
    const float mz3   = fminf(fminf(q3.y, q3.z), q3.w);
    const float tskip = (fabsf(q3.x) >= DENSAFE) ? (mz3 - ZMARGIN) : -INFINITY;

    const int dpx = lane & 7, dpy = lane >> 3;

    for (;;) {
        unsigned int j = 0;
        if (lane == 0) j = atomicAdd(&lticket, 1u);
        j = (unsigned int)__shfl((int)j, 0);
        if (j >= 16u) break;
        // chunk-rotated tile order: phase-shifts the 16 chunk-blocks of the
        // same (b, slice) so their zbest writes warm each other's reads
        const unsigned int jj = (j + (unsigned int)ch) & 15u;

        // 4x4 lattice: tile (row,col) strided 4 in each axis
        const int row = (slice >> 2) + 4 * (int)(jj >> 2);
        const int col = (slice & 3) + 4 * (int)(jj & 3);
        const int ix0 = col * 8, iy0 = row * 8;
        const int ix  = ix0 + dpx, iy = iy0 + dpy;
        const float px = 1.0f - (2.0f * (float)ix + 1.0f) / (float)IMG;
        const float py = 1.0f - (2.0f * (float)iy + 1.0f) / (float)IMG;
        const float pxmax = 1.0f - (2.0f * (float)ix0 + 1.0f) / (float)IMG;
        const float pxmin = 1.0f - (2.0f * (float)(ix0 + 7) + 1.0f) / (float)IMG;
        const float pymax = 1.0f - (2.0f * (float)iy0 + 1.0f) / (float)IMG;
        const float pymin = 1.0f - (2.0f * (float)(iy0 + 7) + 1.0f) / (float)IMG;

        const int gp = b * NPIX + iy * IMG + ix;
        // per-lane bound: current zbest z (may be NaN sentinel) ⊓ own hits
        float zbf = __uint_as_float((unsigned)(zbest[gp] >> 32));

        // conservative half-plane bin test (max over tile rect >= -SLACK)
        bool pass = valid;
        pass &= (g0x * ((c0y ? pymax : pymin) - q0.w)
               - g0y * ((c0x ? pxmin : pxmax) - q0.z)) >= -SLACK;
        pass &= (g1x * ((c1y ? pymax : pymin) - q1.w)
               - g1y * ((c1x ? pxmin : pxmax) - q1.z)) >= -SLACK;
        pass &= (g2x * ((c2y ? pymax : pymin) - q2.w)
               - g2y * ((c2x ? pxmin : pxmax) - q2.z)) >= -SLACK;

        unsigned long long pmin = ~0ULL;
        unsigned long long mask = __ballot(pass);
        while (mask) {
            // pop TWO survivors; evaluate both in one straight-line body
            const int  slA = __builtin_ctzll(mask); mask &= mask - 1;
            const bool h1  = (mask != 0ULL);
            const int  slB = h1 ? __builtin_ctzll(mask) : slA;
            if (h1) mask &= mask - 1;

            // early-z: a skipped face provably loses at every lane; skipping
            // only when BOTH skip keeps the body branch-free (merging a
            // skippable face anyway is harmless — it loses the min).
            const float tzA = rlane(tskip, slA);
            const float tzB = rlane(tskip, slB);
            const bool skA = __all(tzA > zbf);
            const bool skB = h1 ? __all(tzB > zbf) : true;
            if (skA & skB) continue;

            const int fjA = f0 + slA, fjB = f0 + slB;
            const float e0xA = rlane(q0.x, slA), e0yA = rlane(q0.y, slA);
            const float fbxA = rlane(q0.z, slA), fbyA = rlane(q0.w, slA);
            const float e1xA = rlane(q1.x, slA), e1yA = rlane(q1.y, slA);
            const float fcxA = rlane(q1.z, slA), fcyA = rlane(q1.w, slA);
            const float e2xA = rlane(q2.x, slA), e2yA = rlane(q2.y, slA);
            const float faxA = rlane(q2.z, slA), fayA = rlane(q2.w, slA);
            const float denA = rlane(q3.x, slA);
            const float e0xB = rlane(q0.x, slB), e0yB = rlane(q0.y, slB);
            const float fbxB = rlane(q0.z, slB), fbyB = rlane(q0.w, slB);
            const float e1xB = rlane(q1.x, slB), e1yB = rlane(q1.y, slB);
            const float fcxB = rlane(q1.z, slB), fcyB = rlane(q1.w, slB);
            const float e2xB = rlane(q2.x, slB), e2yB = rlane(q2.y, slB);
            const float faxB = rlane(q2.z, slB), fayB = rlane(q2.w, slB);
            const float denB = rlane(q3.x, slB);

            // exact reference edge functions (two independent chains)
            float w0A = e0xA * (py - fbyA) - e0yA * (px - fbxA);
            float w1A = e1xA * (py - fcyA) - e1yA * (px - fcxA);
            float w2A = e2xA * (py - fayA) - e2yA * (px - faxA);
            float w0B = e0xB * (py - fbyB) - e0yB * (px - fbxB);
            float w1B = e1xB * (py - fcyB) - e1yB * (px - fcxB);
            float w2B = e2xB * (py - fayB) - e2yB * (px - faxB);
            // s_i >= 0  <=>  w_i==0 || sign(w_i)==sign(den)  (den != 0 here)
            const unsigned dsA = __float_as_uint(denA) >> 31;
            const unsigned dsB = __float_as_uint(denB) >> 31;
            const bool inA = ((w0A == 0.0f) | ((__float_as_uint(w0A) >> 31) == dsA)) &
                             ((w1A == 0.0f) | ((__float_as_uint(w1A) >> 31) == dsA)) &
                             ((w2A == 0.0f) | ((__float_as_uint(w2A) >> 31) == dsA));
            const bool inB = ((w0B == 0.0f) | ((__float_as_uint(w0B) >> 31) == dsB)) &
                             ((w1B == 0.0f) | ((__float_as_uint(w1B) >> 31) == dsB)) &
                             ((w2B == 0.0f) | ((__float_as_uint(w2B) >> 31) == dsB)) & h1;

            if (__any(inA) | __any(inB)) {
                // exact reference rounding for z; the 6 IEEE divides are
                // independent -> they pipeline inside this one block
                const float azA = rlane(q3.y, slA), bzA = rlane(q3.z, slA),
                            czA = rlane(q3.w, slA);
                const float azB = rlane(q3.y, slB), bzB = rlane(q3.z, slB),
                            czB = rlane(q3.w, slB);
                float s0A = w0A / denA, s1A = w1A / denA, s2A = w2A / denA;
                float s0B = w0B / denB, s1B = w1B / denB, s2B = w2B / denB;
                float zA  = s0A * azA + s1A * bzA + s2A * czA;
                float zB  = s0B * azB + s1B * bzB + s2B * czB;
                if (inA & (zA > 0.0f)) {
                    unsigned long long pk =
                        ((unsigned long long)__float_as_uint(zA) << 32) | (unsigned)fjA;
                    pmin = pmin < pk ? pmin : pk;
                    zbf  = fminf(zbf, zA);
                }
                if (inB & (zB > 0.0f)) {
                    unsigned long long pk =
                        ((unsigned long long)__float_as_uint(zB) << 32) | (unsigned)fjB;
                    pmin = pmin < pk ? pmin : pk;
                    zbf  = fminf(zbf, zB);
                }
            }
        }
        if (pmin != ~0ULL) atomicMin(&zbest[gp], pmin);
    }
}

// Unpack winner; recompute bary + dists from fdata (reference-rounded values).
__global__ __launch_bounds__(256) void pass2(const float* __restrict__ fdata,
                                             const unsigned long long* __restrict__ zbest,
                                             float* __restrict__ out) {
#pragma clang fp contract(off)
    const int gp = blockIdx.x * 256 + threadIdx.x;
    const int b  = gp >> 14;
    const int p  = gp & (NPIX - 1);
    const int ix = p & (IMG - 1), iy = p >> 7;

    unsigned long long packed = zbest[gp];
    float o_face = -1.0f, o_z = -1.0f, o_b0 = -1.0f, o_b1 = -1.0f,
          o_b2 = -1.0f, o_d = -1.0f;

    if (packed != ~0ULL) {
        const int   idx = (int)(unsigned)(packed & 0xffffffffu);
        const float z   = __uint_as_float((unsigned)(packed >> 32));
        const float px  = 1.0f - (2.0f * (float)ix + 1.0f) / (float)IMG;
        const float py  = 1.0f - (2.0f * (float)iy + 1.0f) / (float)IMG;

        const float4* fd4 = (const float4*)(fdata + (((size_t)b * F + idx) << 4));
        float4 q0 = fd4[0], q1 = fd4[1], q2 = fd4[2], q3 = fd4[3];
        float den = q3.x;
        float w0 = q0.x * (py - q0.w) - q0.y * (px - q0.z);
        float w1 = q1.x * (py - q1.w) - q1.y * (px - q1.z);
        float w2 = q2.x * (py - q2.w) - q2.y * (px - q2.z);
        float s0 = w0 / den, s1 = w1 / den, s2 = w2 / den;

        // a=(q2.z,q2.w)  b=(q0.z,q0.w)  c=(q1.z,q1.w): reference-rounded coords
        float d2 = fminf(fminf(seg_dist2(px, py, q2.z, q2.w, q0.z, q0.w),
                               seg_dist2(px, py, q0.z, q0.w, q1.z, q1.w)),
                         seg_dist2(px, py, q1.z, q1.w, q2.z, q2.w));
        o_face = (float)idx; o_z = z;
        o_b0 = s0; o_b1 = s1; o_b2 = s2;
        o_d = -d2;
    }

    out[gp]            = o_face;
    out[B * NPIX + gp] = o_z;
    const int bary_base = 2 * B * NPIX;
    out[bary_base + gp * 3 + 0] = o_b0;
    out[bary_base + gp * 3 + 1] = o_b1;
    out[bary_base + gp * 3 + 2] = o_b2;
    out[5 * B * NPIX + gp] = o_d;
}

} // namespace

extern "C" void kernel_launch(void* const* d_in, const int* in_sizes, int n_in,
                              void* d_out, int out_size, void* d_ws, size_t ws_size,
                              hipStream_t stream) {
    const float* verts = (const float*)d_in[0];  // (B,V,3) f32
    const int*   faces = (const int*)d_in[1];    // (F,3) i32
    float* out = (float*)d_out;

    // ws layout: zbest 512KB | fdata 256KB
    char* ws = (char*)d_ws;
    unsigned long long* zbest = (unsigned long long*)ws;
    float* fdata = (float*)(ws + (size_t)B * NPIX * 8);

    setup_clear<<<B * NPIX / 256, 256, 0, stream>>>(verts, faces, fdata, zbest);
    // 1024 blocks x 8 waves = 8192 waves, all co-resident (32 waves/CU);
    // block = (chunk, image, lattice-slice), 16 tiles via LDS ticket.
    rast<<<1024, 512, 0, stream>>>(fdata, zbest);
    pass2<<<B * NPIX / 256, 256, 0, stream>>>(fdata, zbest, out);
}

// Round 12
// 31.776 us; speedup vs baseline: 1.3602x; 1.3602x over previous
//
#include <hip/hip_runtime.h>
#include <math.h>

namespace {

constexpr int IMG  = 128;
constexpr int NPIX = IMG * IMG;
constexpr int B    = 4;
constexpr int V    = 600;
constexpr int F    = 1000;
constexpr float FOCALF = 1.5f;
constexpr float EPSF   = 1e-8f;
constexpr float SLACK  = 1e-5f;    // >> max rounding error of w (~3e-6)
// rcp-filter: |z~ - z| <= ~3e-6 when |den| >= DENSAFE (sum(s_i) = 1 +- 1e-3);
// ZEPS = 1e-4 gives 30x margin. |den| < DENSAFE faces always take exact path.
constexpr float ZEPS    = 1e-4f;
constexpr float DENSAFE = 1e-3f;

__device__ inline float seg_dist2(float px, float py, float ax, float ay,
                                  float bx, float by) {
#pragma clang fp contract(off)
    float ex = bx - ax, ey = by - ay;
    float dx = px - ax, dy = py - ay;
    float ee = fmaxf(ex * ex + ey * ey, EPSF);
    float t  = (dx * ex + dy * ey) / ee;
    t = fminf(fmaxf(t, 0.0f), 1.0f);
    float rx = dx - t * ex;
    float ry = dy - t * ey;
    return rx * rx + ry * ry;
}

// facedata layout [b][f][16]:
//  0:e0x 1:e0y 2:bx 3:by | 4:e1x 5:e1y 6:cx 7:cy | 8:e2x 9:e2y 10:ax 11:ay |
// 12:den 13:az 14:bz 15:cz      (den==0 marks degenerate/culled)
// Also clears zbest (one u64 per pixel) — fused to save a launch.
__global__ __launch_bounds__(256) void setup_clear(const float* __restrict__ verts,
                                                   const int* __restrict__ faces,
                                                   float* __restrict__ fdata,
                                                   unsigned long long* __restrict__ zbest) {
#pragma clang fp contract(off)
    int t = blockIdx.x * 256 + threadIdx.x;   // grid covers B*NPIX = 65536
    zbest[t] = ~0ULL;
    if (t >= B * F) return;
    int b = t / F, f = t - b * F;
    int i0 = faces[f * 3 + 0], i1 = faces[f * 3 + 1], i2 = faces[f * 3 + 2];
    const float* vb = verts + (size_t)b * V * 3;
    float x0 = vb[i0 * 3], y0 = vb[i0 * 3 + 1], z0 = vb[i0 * 3 + 2];
    float x1 = vb[i1 * 3], y1 = vb[i1 * 3 + 1], z1 = vb[i1 * 3 + 2];
    float x2 = vb[i2 * 3], y2 = vb[i2 * 3 + 1], z2 = vb[i2 * 3 + 2];
    // exact reference projection
    float ax = (FOCALF * x0) / z0, ay = (FOCALF * y0) / z0;
    float bx = (FOCALF * x1) / z1, by = (FOCALF * y1) / z1;
    float cx = (FOCALF * x2) / z2, cy = (FOCALF * y2) / z2;
    // edge vectors (identical rounding to reference's inline subtractions)
    float e0x = cx - bx, e0y = cy - by;   // edge for w0 (v1->v2), base b
    float e1x = ax - cx, e1y = ay - cy;   // edge for w1 (v2->v0), base c
    float e2x = bx - ax, e2y = by - ay;   // edge for w2 (v0->v1), base a
    float den = e2x * (cy - ay) - e2y * (cx - ax);   // == reference area tree
    if (!(fabsf(den) > EPSF)) den = 0.0f;
    float* o = fdata + ((size_t)t << 4);
    o[0]  = e0x; o[1]  = e0y; o[2]  = bx;  o[3]  = by;
    o[4]  = e1x; o[5]  = e1y; o[6]  = cx;  o[7]  = cy;
    o[8]  = e2x; o[9]  = e2y; o[10] = ax;  o[11] = ay;
    o[12] = den; o[13] = z0;  o[14] = z1;  o[15] = z2;
}

// Fused bin+shade. 1024 blocks x 512 thr (8 waves). Block = (ch, b, slice):
// one 64-face chunk x 16 tiles (4x4 lattice). Faces register-pinned for the
// bin test AND staged once to LDS; the survivor loop broadcasts face data via
// 4x ds_read_b128 at a wave-uniform address (DS pipe, off the VALU).
// rcp-prefilter: cheap z~ (rcp-based) decides provably-safe skips; only
// faces that might improve some lane's bound run the bit-exact IEEE path.
__global__ __launch_bounds__(512, 8) void rast(const float* __restrict__ fdata,
                                               unsigned long long* __restrict__ zbest) {
#pragma clang fp contract(off)
    __shared__ float4 sface[64 * 4];     // 4 KB: this block's chunk
    __shared__ unsigned int lticket;
    const int tid  = threadIdx.x;
    const int lane = tid & 63;
    const int bk   = blockIdx.x;
    const int ch   = bk & 15;          // face chunk
    const int b    = (bk >> 4) & 3;    // image
    const int slice = bk >> 6;         // 0..15 -> 4x4 lattice phase
    if (tid == 0) lticket = 0u;

    // pin this chunk's face data: one face per lane, lives in VGPRs
    const int f0 = ch * 64;
    const int sz = min(64, F - f0);    // 64, last chunk 40
    const int fl = min(f0 + lane, F - 1);
    const float4* fd4 = (const float4*)(fdata + (((size_t)b * F + fl) << 4));
    const float4 q0 = fd4[0], q1 = fd4[1], q2 = fd4[2], q3 = fd4[3];
    // stage to LDS once (wave 0 only; all 8 waves share the same chunk)
    if (tid < 64) {
        sface[tid * 4 + 0] = q0;
        sface[tid * 4 + 1] = q1;
        sface[tid * 4 + 2] = q2;
        sface[tid * 4 + 3] = q3;
    }
    __syncthreads();

    const bool valid = (lane < sz) & (q3.x != 0.0f);
    const float s = q3.x > 0.0f ? 1.0f : -1.0f;
    // sign-folded gradients + corner-select bits: fixed per lane, once
    const float g0x = s * q0.x, g0y = s * q0.y;
    const float g1x = s * q1.x, g1y = s * q1.y;
    const float g2x = s * q2.x, g2y = s * q2.y;
    const bool c0y = g0x >= 0.0f, c0x = g0y >= 0.0f;
    const bool c1y = g1x >= 0.0f, c1x = g1y >= 0.0f;
    const bool c2y = g2x >= 0.0f, c2x = g2y >= 0.0f;

    const int dpx = lane & 7, dpy = lane >> 3;

    for (;;) {
        unsigned int j = 0;
        if (lane == 0) j = atomicAdd(&lticket, 1u);
        j = (unsigned int)__shfl((int)j, 0);
        if (j >= 16u) break;
        // chunk-rotated tile order: phase-shifts the 16 chunk-blocks of the
        // same (b, slice) so their zbest writes warm each other's reads
        const unsigned int jj = (j + (unsigned int)ch) & 15u;

        // 4x4 lattice: tile (row,col) strided 4 in each axis
        const int row = (slice >> 2) + 4 * (int)(jj >> 2);
        const int col = (slice & 3) + 4 * (int)(jj & 3);
        const int ix0 = col * 8, iy0 = row * 8;
        const int ix  = ix0 + dpx, iy = iy0 + dpy;
        const float px = 1.0f - (2.0f * (float)ix + 1.0f) / (float)IMG;
        const float py = 1.0f - (2.0f * (float)iy + 1.0f) / (float)IMG;
        const float pxmax = 1.0f - (2.0f * (float)ix0 + 1.0f) / (float)IMG;
        const float pxmin = 1.0f - (2.0f * (float)(ix0 + 7) + 1.0f) / (float)IMG;
        const float pymax = 1.0f - (2.0f * (float)iy0 + 1.0f) / (float)IMG;
        const float pymin = 1.0f - (2.0f * (float)(iy0 + 7) + 1.0f) / (float)IMG;

        const int gp = b * NPIX + iy * IMG + ix;
        // per-lane bound: current zbest z; +INF when no hit yet (sentinel)
        const unsigned ztop = (unsigned)(zbest[gp] >> 32);
        float zbf  = (ztop == 0xFFFFFFFFu) ? INFINITY : __uint_as_float(ztop);
        float zbfp = zbf + ZEPS;   // skip threshold (INF stays INF)

        // conservative half-plane bin test (max over tile rect >= -SLACK)
        bool pass = valid;
        pass &= (g0x * ((c0y ? pymax : pymin) - q0.w)
               - g0y * ((c0x ? pxmin : pxmax) - q0.z)) >= -SLACK;
        pass &= (g1x * ((c1y ? pymax : pymin) - q1.w)
               - g1y * ((c1x ? pxmin : pxmax) - q1.z)) >= -SLACK;
        pass &= (g2x * ((c2y ? pymax : pymin) - q2.w)
               - g2y * ((c2x ? pxmin : pxmax) - q2.z)) >= -SLACK;

        unsigned long long pmin = ~0ULL;
        unsigned long long mask = __ballot(pass);
        while (mask) {
            const int sl = __builtin_ctzll(mask);
            mask &= mask - 1;
            // broadcast face data from LDS (wave-uniform addr -> no conflict)
            const float4 r0 = sface[sl * 4 + 0];
            const float4 r1 = sface[sl * 4 + 1];
            const float4 r2 = sface[sl * 4 + 2];
            const float4 r3 = sface[sl * 4 + 3];
            const float den = r3.x;
            // exact reference edge functions (shared by filter & exact path)
            float w0 = r0.x * (py - r0.w) - r0.y * (px - r0.z);
            float w1 = r1.x * (py - r1.w) - r1.y * (px - r1.z);
            float w2 = r2.x * (py - r2.w) - r2.y * (px - r2.z);

            // ---- cheap rcp-prefilter (provably-safe skips only) ----
            // conservative inside: !(w*den < 0) covers w==+-0 and sign-match
            const bool i0 = !(w0 * den < 0.0f);
            const bool i1 = !(w1 * den < 0.0f);
            const bool i2 = !(w2 * den < 0.0f);
            const float rd  = __builtin_amdgcn_rcpf(den);
            const float zt  = (w0 * rd) * r3.y + (w1 * rd) * r3.z + (w2 * rd) * r3.w;
            const bool densmall = fabsf(den) < DENSAFE;    // error bound invalid
            const bool need = (i0 & i1 & i2) &
                              (densmall | ((zt < zbfp) & (zt > -ZEPS)));
            if (__any(need)) {
                // ---- bit-exact reference path ----
                const unsigned ds = __float_as_uint(den) >> 31;
                const bool in0 = (w0 == 0.0f) | ((__float_as_uint(w0) >> 31) == ds);
                const bool in1 = (w1 == 0.0f) | ((__float_as_uint(w1) >> 31) == ds);
                const bool in2 = (w2 == 0.0f) | ((__float_as_uint(w2) >> 31) == ds);
                if (in0 & in1 & in2) {
                    // exact reference rounding for z (3 IEEE divides)
                    float s0 = w0 / den, s1 = w1 / den, s2 = w2 / den;
                    float z  = s0 * r3.y + s1 * r3.z + s2 * r3.w;
                    if (z > 0.0f) {
                        unsigned long long pk =
                            ((unsigned long long)__float_as_uint(z) << 32) |
                            (unsigned)(f0 + sl);
                        pmin = pmin < pk ? pmin : pk;
                        zbf  = fminf(zbf, z);
                        zbfp = zbf + ZEPS;
                    }
                }
            }
        }
        if (pmin != ~0ULL) atomicMin(&zbest[gp], pmin);
    }
}

// Unpack winner; recompute bary + dists from fdata (reference-rounded values).
__global__ __launch_bounds__(256) void pass2(const float* __restrict__ fdata,
                                             const unsigned long long* __restrict__ zbest,
                                             float* __restrict__ out) {
#pragma clang fp contract(off)
    const int gp = blockIdx.x * 256 + threadIdx.x;
    const int b  = gp >> 14;
    const int p  = gp & (NPIX - 1);
    const int ix = p & (IMG - 1), iy = p >> 7;

    unsigned long long packed = zbest[gp];
    float o_face = -1.0f, o_z = -1.0f, o_b0 = -1.0f, o_b1 = -1.0f,
          o_b2 = -1.0f, o_d = -1.0f;

    if (packed != ~0ULL) {
        const int   idx = (int)(unsigned)(packed & 0xffffffffu);
        const float z   = __uint_as_float((unsigned)(packed >> 32));
        const float px  = 1.0f - (2.0f * (float)ix + 1.0f) / (float)IMG;
        const float py  = 1.0f - (2.0f * (float)iy + 1.0f) / (float)IMG;

        const float4* fd4 = (const float4*)(fdata + (((size_t)b * F + idx) << 4));
        float4 q0 = fd4[0], q1 = fd4[1], q2 = fd4[2], q3 = fd4[3];
        float den = q3.x;
        float w0 = q0.x * (py - q0.w) - q0.y * (px - q0.z);
        float w1 = q1.x * (py - q1.w) - q1.y * (px - q1.z);
        float w2 = q2.x * (py - q2.w) - q2.y * (px - q2.z);
        float s0 = w0 / den, s1 = w1 / den, s2 = w2 / den;

        // a=(q2.z,q2.w)  b=(q0.z,q0.w)  c=(q1.z,q1.w): reference-rounded coords
        float d2 = fminf(fminf(seg_dist2(px, py, q2.z, q2.w, q0.z, q0.w),
                               seg_dist2(px, py, q0.z, q0.w, q1.z, q1.w)),
                         seg_dist2(px, py, q1.z, q1.w, q2.z, q2.w));
        o_face = (float)idx; o_z = z;
        o_b0 = s0; o_b1 = s1; o_b2 = s2;
        o_d = -d2;
    }

    out[gp]            = o_face;
    out[B * NPIX + gp] = o_z;
    const int bary_base = 2 * B * NPIX;
    out[bary_base + gp * 3 + 0] = o_b0;
    out[bary_base + gp * 3 + 1] = o_b1;
    out[bary_base + gp * 3 + 2] = o_b2;
    out[5 * B * NPIX + gp] = o_d;
}

} // namespace

extern "C" void kernel_launch(void* const* d_in, const int* in_sizes, int n_in,
                              void* d_out, int out_size, void* d_ws, size_t ws_size,
                              hipStream_t stream) {
    const float* verts = (const float*)d_in[0];  // (B,V,3) f32
    const int*   faces = (const int*)d_in[1];    // (F,3) i32
    float* out = (float*)d_out;

    // ws layout: zbest 512KB | fdata 256KB
    char* ws = (char*)d_ws;
    unsigned long long* zbest = (unsigned long long*)ws;
    float* fdata = (float*)(ws + (size_t)B * NPIX * 8);

    setup_clear<<<B * NPIX / 256, 256, 0, stream>>>(verts, faces, fdata, zbest);
    // 1024 blocks x 8 waves = 8192 waves, all co-resident (32 waves/CU);
    // block = (chunk, image, lattice-slice), 16 tiles via LDS ticket.
    rast<<<1024, 512, 0, stream>>>(fdata, zbest);
    pass2<<<B * NPIX / 256, 256, 0, stream>>>(fdata, zbest, out);
}